// Round 1
// baseline (358.136 us; speedup 1.0000x reference)
//
#include <hip/hip_runtime.h>
#include <hip/hip_bf16.h>

#define TOKENS 2048
#define DIM 512
#define NEXP 16
#define HID 2048
#define MT 64
#define MAX_TILES (TOKENS * 2 / MT + NEXP) /* 80 */
#define MAX_ROWS (MAX_TILES * MT)          /* 5120 */

typedef unsigned short ushort_t;
typedef __attribute__((ext_vector_type(8))) __bf16 bf16x8;
typedef __attribute__((ext_vector_type(4))) float f32x4;

struct Meta {
  int counts[NEXP];
  int poff[NEXP];
  int vend[NEXP];
  int cursors[NEXP];
  int tile_expert[MAX_TILES];
  int tile_row0[MAX_TILES];
  int total_tiles;
  int total_rows;
};

// workspace byte offsets
#define OFF_META 0
#define OFF_SEL 4096
#define OFF_WTS 20480
#define OFF_LTOK 36864
#define OFF_LW 57344
#define OFF_MU 77824
#define OFF_RS 98304
#define OFF_XBF 131072
#define OFF_H 2228224
// total ws use: 2228224 + 5120*2048*2 = 23,199,744 bytes

__device__ __forceinline__ ushort_t f2b(float f) {
  __bf16 b = (__bf16)f;
  return __builtin_bit_cast(unsigned short, b);
}
__device__ __forceinline__ float b2f(ushort_t u) {
  return __builtin_bit_cast(float, (unsigned)u << 16);
}

// ---------------- router: logits, top-2, softmax, bf16 cast of x ------------
__global__ __launch_bounds__(256) void router_k(
    const float* __restrict__ x, const float* __restrict__ Wg,
    ushort_t* __restrict__ xbf, int* __restrict__ sel, float* __restrict__ wts,
    Meta* __restrict__ mt) {
  int lane = threadIdx.x & 63, wave = threadIdx.x >> 6;
  int tok = blockIdx.x * 4 + wave;
  const float* xr = x + (size_t)tok * DIM + lane * 8;
  float4 xa = *(const float4*)xr;
  float4 xb = *(const float4*)(xr + 4);
  float xv[8] = {xa.x, xa.y, xa.z, xa.w, xb.x, xb.y, xb.z, xb.w};
  union { ushort_t u[8]; uint4 v; } pk;
#pragma unroll
  for (int j = 0; j < 8; j++) pk.u[j] = f2b(xv[j]);
  *(uint4*)(xbf + (size_t)tok * DIM + lane * 8) = pk.v;

  float acc[NEXP];
#pragma unroll
  for (int e = 0; e < NEXP; e++) acc[e] = 0.f;
#pragma unroll
  for (int j = 0; j < 8; j++) {
    const float* wr = Wg + (size_t)(lane * 8 + j) * NEXP;
    float xd = xv[j];
#pragma unroll
    for (int e = 0; e < NEXP; e++) acc[e] += xd * wr[e];
  }
#pragma unroll
  for (int off = 32; off; off >>= 1) {
#pragma unroll
    for (int e = 0; e < NEXP; e++) acc[e] += __shfl_down(acc[e], off);
  }
  if (lane == 0) {
    int i0 = 0;
    float v0 = acc[0];
#pragma unroll
    for (int e = 1; e < NEXP; e++)
      if (acc[e] > v0) { v0 = acc[e]; i0 = e; }
    int i1 = -1;
    float v1 = -3.4e38f;
#pragma unroll
    for (int e = 0; e < NEXP; e++)
      if (e != i0 && acc[e] > v1) { v1 = acc[e]; i1 = e; }
    float ex = __expf(v1 - v0);
    float w0 = 1.f / (1.f + ex);
    sel[2 * tok] = i0;
    sel[2 * tok + 1] = i1;
    wts[2 * tok] = w0;
    wts[2 * tok + 1] = ex / (1.f + ex);
    atomicAdd(&mt->counts[i0], 1);
    atomicAdd(&mt->counts[i1], 1);
  }
}

// ---------------- meta: padded offsets, tile map, pad-row fill --------------
__global__ void build_k(Meta* mt, int* ltok, float* lw) {
  if (threadIdx.x == 0) {
    int off = 0, tiles = 0;
    for (int e = 0; e < NEXP; e++) {
      int c = mt->counts[e];
      mt->poff[e] = off;
      mt->cursors[e] = off;
      mt->vend[e] = off + c;
      int nt = (c + MT - 1) / MT;
      for (int i = 0; i < nt; i++) {
        mt->tile_expert[tiles] = e;
        mt->tile_row0[tiles] = off + i * MT;
        tiles++;
      }
      int pe = off + nt * MT;
      for (int r = off + c; r < pe; r++) { ltok[r] = -1; lw[r] = 0.f; }
      off = pe;
    }
    mt->total_tiles = tiles;
    mt->total_rows = off;
  }
}

// ---------------- scatter tokens into expert row lists ----------------------
__global__ __launch_bounds__(256) void scatter_k(
    Meta* mt, const int* __restrict__ sel, const float* __restrict__ wts,
    int* __restrict__ ltok, float* __restrict__ lw) {
  int t = blockIdx.x * blockDim.x + threadIdx.x;
  if (t >= TOKENS) return;
#pragma unroll
  for (int k = 0; k < 2; k++) {
    int e = sel[2 * t + k];
    int slot = atomicAdd(&mt->cursors[e], 1);
    ltok[slot] = t;
    lw[slot] = wts[2 * t + k];
  }
}

// ---------------- GEMM1: h = silu(x @ W1 + b1), store bf16 ------------------
__global__ __launch_bounds__(256) void ffn1_k(
    const float* __restrict__ W1, const float* __restrict__ b1,
    const Meta* __restrict__ mt, const int* __restrict__ ltok,
    const ushort_t* __restrict__ xbf, ushort_t* __restrict__ hbuf) {
  int tile = blockIdx.x;
  if (tile >= mt->total_tiles) return;
  int e = mt->tile_expert[tile];
  int row0 = mt->tile_row0[tile];
  int h0 = blockIdx.y * 128;
  int valid = mt->vend[e] - row0;
  valid = valid > MT ? MT : valid;

  __shared__ __align__(16) ushort_t As[MT * 40];

  int t = threadIdx.x;
  int lane = t & 63, wave = t >> 6;
  int quad = lane >> 4, l16 = lane & 15;

  int sr = t >> 2, sp = t & 3;
  int stok = ltok[row0 + sr];
  const ushort_t* sx = xbf + (size_t)(stok < 0 ? 0 : stok) * DIM + sp * 8;
  bool sok = stok >= 0;

  int ncol = h0 + wave * 32 + l16;
  const float* bbase = W1 + ((size_t)e * DIM + quad * 8) * HID + ncol;

  f32x4 acc[4][2];
#pragma unroll
  for (int a = 0; a < 4; a++)
#pragma unroll
    for (int b = 0; b < 2; b++) acc[a][b] = {0.f, 0.f, 0.f, 0.f};

  for (int ks = 0; ks < DIM / 32; ks++) {
    int kc = ks * 32;
    uint4 av = {0u, 0u, 0u, 0u};
    if (sok) av = *(const uint4*)(sx + kc);
    __syncthreads();
    *(uint4*)(&As[sr * 40 + sp * 8]) = av;

    const float* bp = bbase + (size_t)kc * HID;
    bf16x8 bfr[2];
#pragma unroll
    for (int nb = 0; nb < 2; nb++) {
#pragma unroll
      for (int j = 0; j < 8; j++) bfr[nb][j] = (__bf16)bp[(size_t)j * HID + nb * 16];
    }
    __syncthreads();
    bf16x8 af[4];
#pragma unroll
    for (int mb = 0; mb < 4; mb++)
      af[mb] = *(const bf16x8*)(&As[(mb * 16 + l16) * 40 + quad * 8]);
#pragma unroll
    for (int mb = 0; mb < 4; mb++)
#pragma unroll
      for (int nb = 0; nb < 2; nb++)
        acc[mb][nb] = __builtin_amdgcn_mfma_f32_16x16x32_bf16(af[mb], bfr[nb], acc[mb][nb], 0, 0, 0);
  }

#pragma unroll
  for (int mb = 0; mb < 4; mb++) {
#pragma unroll
    for (int i = 0; i < 4; i++) {
      int m = mb * 16 + quad * 4 + i;
      if (m < valid) {
        size_t rowg = (size_t)(row0 + m);
#pragma unroll
        for (int nb = 0; nb < 2; nb++) {
          int n = ncol + nb * 16;
          float v = acc[mb][nb][i] + b1[e * HID + n];
          v = v / (1.f + __expf(-v));  // silu
          hbuf[rowg * HID + n] = f2b(v);
        }
      }
    }
  }
}

// ---------------- per-row LayerNorm stats -----------------------------------
__global__ __launch_bounds__(256) void stats_k(
    const int* __restrict__ ltok, const ushort_t* __restrict__ hbuf,
    float* __restrict__ muv, float* __restrict__ rsv) {
  int row = blockIdx.x;
  if (ltok[row] < 0) return;  // pad / unused row
  const ushort_t* hr = hbuf + (size_t)row * HID;
  int t = threadIdx.x;
  union { uint4 v; ushort_t u[8]; } ld;
  ld.v = *(const uint4*)(hr + t * 8);
  float s1 = 0.f, s2 = 0.f;
#pragma unroll
  for (int j = 0; j < 8; j++) {
    float f = b2f(ld.u[j]);
    s1 += f;
    s2 += f * f;
  }
#pragma unroll
  for (int off = 32; off; off >>= 1) {
    s1 += __shfl_down(s1, off);
    s2 += __shfl_down(s2, off);
  }
  __shared__ float red[8];
  int lane = t & 63, wave = t >> 6;
  if (lane == 0) { red[wave] = s1; red[4 + wave] = s2; }
  __syncthreads();
  if (t == 0) {
    float a = red[0] + red[1] + red[2] + red[3];
    float b = red[4] + red[5] + red[6] + red[7];
    float mu = a / (float)HID;
    float var = b / (float)HID - mu * mu;
    muv[row] = mu;
    rsv[row] = rsqrtf(var + 1e-5f);
  }
}

// ---------------- GEMM2: out[t] += w * (LN(h) @ W2 + b2) --------------------
__global__ __launch_bounds__(256) void ffn2_k(
    const float* __restrict__ W2, const float* __restrict__ b2,
    const float* __restrict__ lng, const float* __restrict__ lnb,
    const Meta* __restrict__ mt, const int* __restrict__ ltok,
    const float* __restrict__ lw, const ushort_t* __restrict__ hbuf,
    const float* __restrict__ muv, const float* __restrict__ rsv,
    float* __restrict__ out) {
  int tile = blockIdx.x;
  if (tile >= mt->total_tiles) return;
  int e = mt->tile_expert[tile];
  int row0 = mt->tile_row0[tile];
  int n0 = blockIdx.y * 64;
  int valid = mt->vend[e] - row0;
  valid = valid > MT ? MT : valid;

  __shared__ __align__(16) ushort_t As[MT * 40];

  int t = threadIdx.x;
  int lane = t & 63, wave = t >> 6;
  int quad = lane >> 4, l16 = lane & 15;

  int sr = t >> 2, sp = t & 3;
  size_t srow = (size_t)(row0 + sr);
  const ushort_t* hr = hbuf + srow * HID + sp * 8;
  float smu = muv[srow], srs = rsv[srow];
  const float* gp = lng + (size_t)e * HID + sp * 8;
  const float* cp = lnb + (size_t)e * HID + sp * 8;

  int ncol = n0 + wave * 16 + l16;
  const float* bbase = W2 + ((size_t)e * HID + quad * 8) * DIM + ncol;

  f32x4 acc[4];
#pragma unroll
  for (int a = 0; a < 4; a++) acc[a] = {0.f, 0.f, 0.f, 0.f};

  for (int ks = 0; ks < HID / 32; ks++) {
    int kc = ks * 32;
    union { uint4 v; ushort_t u[8]; } hv;
    hv.v = *(const uint4*)(hr + kc);
    float4 g0 = *(const float4*)(gp + kc);
    float4 g1 = *(const float4*)(gp + kc + 4);
    float4 c0 = *(const float4*)(cp + kc);
    float4 c1 = *(const float4*)(cp + kc + 4);
    union { ushort_t u[8]; uint4 v; } pk;
    {
      float gs[8] = {g0.x, g0.y, g0.z, g0.w, g1.x, g1.y, g1.z, g1.w};
      float cs[8] = {c0.x, c0.y, c0.z, c0.w, c1.x, c1.y, c1.z, c1.w};
#pragma unroll
      for (int j = 0; j < 8; j++) {
        float f = (b2f(hv.u[j]) - smu) * srs;
        pk.u[j] = f2b(f * gs[j] + cs[j]);
      }
    }
    __syncthreads();
    *(uint4*)(&As[sr * 40 + sp * 8]) = pk.v;

    const float* bp = bbase + (size_t)kc * DIM;
    bf16x8 bfr;
#pragma unroll
    for (int j = 0; j < 8; j++) bfr[j] = (__bf16)bp[(size_t)j * DIM];
    __syncthreads();
    bf16x8 af[4];
#pragma unroll
    for (int mb = 0; mb < 4; mb++)
      af[mb] = *(const bf16x8*)(&As[(mb * 16 + l16) * 40 + quad * 8]);
#pragma unroll
    for (int mb = 0; mb < 4; mb++)
      acc[mb] = __builtin_amdgcn_mfma_f32_16x16x32_bf16(af[mb], bfr, acc[mb], 0, 0, 0);
  }

#pragma unroll
  for (int mb = 0; mb < 4; mb++) {
#pragma unroll
    for (int i = 0; i < 4; i++) {
      int m = mb * 16 + quad * 4 + i;
      if (m < valid) {
        int tok = ltok[row0 + m];
        float w = lw[row0 + m];
        float v = acc[mb][i] + b2[e * DIM + ncol];
        atomicAdd(out + (size_t)tok * DIM + ncol, w * v);
      }
    }
  }
}

extern "C" void kernel_launch(void* const* d_in, const int* in_sizes, int n_in,
                              void* d_out, int out_size, void* d_ws, size_t ws_size,
                              hipStream_t stream) {
  const float* x = (const float*)d_in[0];
  const float* Wg = (const float*)d_in[1];
  const float* W1 = (const float*)d_in[2];
  const float* b1 = (const float*)d_in[3];
  const float* lng = (const float*)d_in[4];
  const float* lnb = (const float*)d_in[5];
  const float* W2 = (const float*)d_in[6];
  const float* b2 = (const float*)d_in[7];
  float* out = (float*)d_out;

  char* ws = (char*)d_ws;
  Meta* meta = (Meta*)(ws + OFF_META);
  int* sel = (int*)(ws + OFF_SEL);
  float* wts = (float*)(ws + OFF_WTS);
  int* ltok = (int*)(ws + OFF_LTOK);
  float* lw = (float*)(ws + OFF_LW);
  float* muv = (float*)(ws + OFF_MU);
  float* rsv = (float*)(ws + OFF_RS);
  ushort_t* xbf = (ushort_t*)(ws + OFF_XBF);
  ushort_t* hbuf = (ushort_t*)(ws + OFF_H);

  hipMemsetAsync(ws, 0, 4096, stream);                                  // zero Meta (counts)
  hipMemsetAsync(d_out, 0, (size_t)TOKENS * DIM * sizeof(float), stream);

  router_k<<<TOKENS / 4, 256, 0, stream>>>(x, Wg, xbf, sel, wts, meta);
  build_k<<<1, 64, 0, stream>>>(meta, ltok, lw);
  scatter_k<<<(TOKENS + 255) / 256, 256, 0, stream>>>(meta, sel, wts, ltok, lw);
  ffn1_k<<<dim3(MAX_TILES, HID / 128), 256, 0, stream>>>(W1, b1, meta, ltok, xbf, hbuf);
  stats_k<<<MAX_ROWS, 256, 0, stream>>>(ltok, hbuf, muv, rsv);
  ffn2_k<<<dim3(MAX_TILES, DIM / 64), 256, 0, stream>>>(W2, b2, lng, lnb, meta, ltok,
                                                        lw, hbuf, muv, rsv, out);
}

// Round 2
// 346.933 us; speedup vs baseline: 1.0323x; 1.0323x over previous
//
#include <hip/hip_runtime.h>
#include <hip/hip_bf16.h>

#define TOKENS 2048
#define DIM 512
#define NEXP 16
#define HID 2048
#define MT 64
#define MAX_TILES 80
#define MAX_ROWS 5120

typedef unsigned short ushort_t;
typedef __attribute__((ext_vector_type(8))) __bf16 bf16x8;
typedef __attribute__((ext_vector_type(4))) float f32x4;

struct Meta {
  int counts[NEXP];
  int poff[NEXP];
  int vend[NEXP];
  int cursors[NEXP];
  int tile_expert[MAX_TILES];
  int tile_row0[MAX_TILES];
  int total_tiles;
  int total_rows;
};

// workspace byte offsets
#define OFF_META 0
#define OFF_SEL 4096
#define OFF_WTS 20480
#define OFF_LTOK 36864
#define OFF_LW 57344
#define OFF_MU 77824
#define OFF_RS 98304
#define OFF_XBF 131072        /* 2048*512*2      = 2,097,152  -> ends 2,228,224 */
#define OFF_H 2228224         /* 5120*2048*2     = 20,971,520 -> ends 23,199,744 */
#define OFF_W1T 23199744      /* 16*2048*512*2   = 33,554,432 -> ends 56,754,176 */
#define OFF_W2T 56754176      /* 16*512*2048*2   = 33,554,432 -> ends 90,308,608 */

__device__ __forceinline__ ushort_t f2b(float f) {
  __bf16 b = (__bf16)f;
  return __builtin_bit_cast(unsigned short, b);
}
__device__ __forceinline__ float b2f(ushort_t u) {
  return __builtin_bit_cast(float, (unsigned)u << 16);
}

// ---------- weight convert+transpose: src[E][K][N] f32 -> dst[E][N][K] bf16 --
__global__ __launch_bounds__(256) void wconv_k(const float* __restrict__ src,
                                               ushort_t* __restrict__ dst,
                                               int K, int N, int nnt) {
  int e = blockIdx.y;
  int kt = blockIdx.x / nnt, ntb = blockIdx.x % nnt;
  int k0 = kt * 32, n0 = ntb * 32;
  __shared__ ushort_t Ls[32 * 33];
  int t = threadIdx.x;
  int r = t >> 3, c4 = (t & 7) * 4;
  const float* sp = src + ((size_t)e * K + k0 + r) * N + n0 + c4;
  float4 v = *(const float4*)sp;
  Ls[r * 33 + c4 + 0] = f2b(v.x);
  Ls[r * 33 + c4 + 1] = f2b(v.y);
  Ls[r * 33 + c4 + 2] = f2b(v.z);
  Ls[r * 33 + c4 + 3] = f2b(v.w);
  __syncthreads();
  union { ushort_t u[4]; unsigned long long q; } o;
#pragma unroll
  for (int i = 0; i < 4; i++) o.u[i] = Ls[(c4 + i) * 33 + r];
  *(unsigned long long*)(dst + ((size_t)e * N + n0 + r) * K + k0 + c4) = o.q;
}

// ---------------- router: logits, top-2, softmax, bf16 cast of x ------------
__global__ __launch_bounds__(256) void router_k(
    const float* __restrict__ x, const float* __restrict__ Wg,
    ushort_t* __restrict__ xbf, int* __restrict__ sel, float* __restrict__ wts,
    Meta* __restrict__ mt) {
  int lane = threadIdx.x & 63, wave = threadIdx.x >> 6;
  int tok = blockIdx.x * 4 + wave;
  const float* xr = x + (size_t)tok * DIM + lane * 8;
  float4 xa = *(const float4*)xr;
  float4 xb = *(const float4*)(xr + 4);
  float xv[8] = {xa.x, xa.y, xa.z, xa.w, xb.x, xb.y, xb.z, xb.w};
  union { ushort_t u[8]; uint4 v; } pk;
#pragma unroll
  for (int j = 0; j < 8; j++) pk.u[j] = f2b(xv[j]);
  *(uint4*)(xbf + (size_t)tok * DIM + lane * 8) = pk.v;

  float acc[NEXP];
#pragma unroll
  for (int e = 0; e < NEXP; e++) acc[e] = 0.f;
#pragma unroll
  for (int j = 0; j < 8; j++) {
    const float* wr = Wg + (size_t)(lane * 8 + j) * NEXP;
    float xd = xv[j];
#pragma unroll
    for (int e = 0; e < NEXP; e++) acc[e] += xd * wr[e];
  }
#pragma unroll
  for (int off = 32; off; off >>= 1) {
#pragma unroll
    for (int e = 0; e < NEXP; e++) acc[e] += __shfl_down(acc[e], off);
  }
  if (lane == 0) {
    int i0 = 0;
    float v0 = acc[0];
#pragma unroll
    for (int e = 1; e < NEXP; e++)
      if (acc[e] > v0) { v0 = acc[e]; i0 = e; }
    int i1 = -1;
    float v1 = -3.4e38f;
#pragma unroll
    for (int e = 0; e < NEXP; e++)
      if (e != i0 && acc[e] > v1) { v1 = acc[e]; i1 = e; }
    float ex = __expf(v1 - v0);
    float w0 = 1.f / (1.f + ex);
    sel[2 * tok] = i0;
    sel[2 * tok + 1] = i1;
    wts[2 * tok] = w0;
    wts[2 * tok + 1] = ex / (1.f + ex);
    atomicAdd(&mt->counts[i0], 1);
    atomicAdd(&mt->counts[i1], 1);
  }
}

// ---------------- meta: padded offsets, tile map, pad-row fill --------------
__global__ __launch_bounds__(256) void build_k(Meta* mt, int* ltok, float* lw) {
  __shared__ int sv[NEXP], spe[NEXP];
  int t = threadIdx.x;
  if (t == 0) {
    int off = 0, tiles = 0;
    for (int e = 0; e < NEXP; e++) {
      int c = mt->counts[e];
      mt->poff[e] = off;
      mt->cursors[e] = off;
      mt->vend[e] = off + c;
      sv[e] = off + c;
      int nt = (c + MT - 1) / MT;
      for (int i = 0; i < nt; i++) {
        mt->tile_expert[tiles] = e;
        mt->tile_row0[tiles] = off + i * MT;
        tiles++;
      }
      off += nt * MT;
      spe[e] = off;
    }
    mt->total_tiles = tiles;
    mt->total_rows = off;
  }
  __syncthreads();
#pragma unroll
  for (int e = 0; e < NEXP; e++) {
    int s = sv[e], pe = spe[e];
    for (int r = s + t; r < pe; r += 256) { ltok[r] = -1; lw[r] = 0.f; }
  }
}

// ---------------- scatter tokens into expert row lists ----------------------
__global__ __launch_bounds__(256) void scatter_k(
    Meta* mt, const int* __restrict__ sel, const float* __restrict__ wts,
    int* __restrict__ ltok, float* __restrict__ lw) {
  int t = blockIdx.x * blockDim.x + threadIdx.x;
  if (t >= TOKENS) return;
#pragma unroll
  for (int k = 0; k < 2; k++) {
    int e = sel[2 * t + k];
    int slot = atomicAdd(&mt->cursors[e], 1);
    ltok[slot] = t;
    lw[slot] = wts[2 * t + k];
  }
}

// ---------------- GEMM1: h = silu(x @ W1 + b1), store bf16 ------------------
// W1t: [E][H][D] bf16 (k=D contiguous)
__global__ __launch_bounds__(256) void ffn1_k(
    const ushort_t* __restrict__ W1t, const float* __restrict__ b1,
    const Meta* __restrict__ mt, const int* __restrict__ ltok,
    const ushort_t* __restrict__ xbf, ushort_t* __restrict__ hbuf) {
  int tile = blockIdx.x;
  if (tile >= mt->total_tiles) return;
  int e = mt->tile_expert[tile];
  int row0 = mt->tile_row0[tile];
  int h0 = blockIdx.y * 128;
  int valid = mt->vend[e] - row0;
  valid = valid > MT ? MT : valid;

  __shared__ __align__(16) ushort_t As[MT * 40];

  int t = threadIdx.x;
  int lane = t & 63, wave = t >> 6;
  int quad = lane >> 4, l16 = lane & 15;

  int sr = t >> 2, sp = t & 3;
  int stok = ltok[row0 + sr];
  const ushort_t* sx = xbf + (size_t)(stok < 0 ? 0 : stok) * DIM + sp * 8;
  bool sok = stok >= 0;

  int ncol = h0 + wave * 32 + l16;
  const ushort_t* bb = W1t + ((size_t)e * HID + ncol) * DIM + quad * 8;

  f32x4 acc[4][2];
#pragma unroll
  for (int a = 0; a < 4; a++)
#pragma unroll
    for (int b = 0; b < 2; b++) acc[a][b] = {0.f, 0.f, 0.f, 0.f};

  for (int ks = 0; ks < DIM / 32; ks++) {
    int kc = ks * 32;
    uint4 av = {0u, 0u, 0u, 0u};
    if (sok) av = *(const uint4*)(sx + kc);
    __syncthreads();
    *(uint4*)(&As[sr * 40 + sp * 8]) = av;

    bf16x8 bfr[2];
    bfr[0] = *(const bf16x8*)(bb + kc);
    bfr[1] = *(const bf16x8*)(bb + (size_t)16 * DIM + kc);
    __syncthreads();
    bf16x8 af[4];
#pragma unroll
    for (int mb = 0; mb < 4; mb++)
      af[mb] = *(const bf16x8*)(&As[(mb * 16 + l16) * 40 + quad * 8]);
#pragma unroll
    for (int mb = 0; mb < 4; mb++)
#pragma unroll
      for (int nb = 0; nb < 2; nb++)
        acc[mb][nb] = __builtin_amdgcn_mfma_f32_16x16x32_bf16(af[mb], bfr[nb], acc[mb][nb], 0, 0, 0);
  }

#pragma unroll
  for (int mb = 0; mb < 4; mb++) {
#pragma unroll
    for (int i = 0; i < 4; i++) {
      int m = mb * 16 + quad * 4 + i;
      if (m < valid) {
        size_t rowg = (size_t)(row0 + m);
#pragma unroll
        for (int nb = 0; nb < 2; nb++) {
          int n = ncol + nb * 16;
          float v = acc[mb][nb][i] + b1[e * HID + n];
          v = v / (1.f + __expf(-v));  // silu
          hbuf[rowg * HID + n] = f2b(v);
        }
      }
    }
  }
}

// ---------------- per-row LayerNorm stats -----------------------------------
__global__ __launch_bounds__(256) void stats_k(
    const int* __restrict__ ltok, const ushort_t* __restrict__ hbuf,
    float* __restrict__ muv, float* __restrict__ rsv) {
  int row = blockIdx.x;
  if (ltok[row] < 0) return;  // pad / unused row
  const ushort_t* hr = hbuf + (size_t)row * HID;
  int t = threadIdx.x;
  union { uint4 v; ushort_t u[8]; } ld;
  ld.v = *(const uint4*)(hr + t * 8);
  float s1 = 0.f, s2 = 0.f;
#pragma unroll
  for (int j = 0; j < 8; j++) {
    float f = b2f(ld.u[j]);
    s1 += f;
    s2 += f * f;
  }
#pragma unroll
  for (int off = 32; off; off >>= 1) {
    s1 += __shfl_down(s1, off);
    s2 += __shfl_down(s2, off);
  }
  __shared__ float red[8];
  int lane = t & 63, wave = t >> 6;
  if (lane == 0) { red[wave] = s1; red[4 + wave] = s2; }
  __syncthreads();
  if (t == 0) {
    float a = red[0] + red[1] + red[2] + red[3];
    float b = red[4] + red[5] + red[6] + red[7];
    float mu = a / (float)HID;
    float var = b / (float)HID - mu * mu;
    muv[row] = mu;
    rsv[row] = rsqrtf(var + 1e-5f);
  }
}

// ---------------- GEMM2: out[t] += w * (LN(h) @ W2 + b2) --------------------
// W2t: [E][D][H] bf16 (k=H contiguous). K split in 2 via blockIdx.z.
__global__ __launch_bounds__(256) void ffn2_k(
    const ushort_t* __restrict__ W2t, const float* __restrict__ b2,
    const float* __restrict__ lng, const float* __restrict__ lnb,
    const Meta* __restrict__ mt, const int* __restrict__ ltok,
    const float* __restrict__ lw, const ushort_t* __restrict__ hbuf,
    const float* __restrict__ muv, const float* __restrict__ rsv,
    float* __restrict__ out) {
  int tile = blockIdx.x;
  if (tile >= mt->total_tiles) return;
  int e = mt->tile_expert[tile];
  int row0 = mt->tile_row0[tile];
  int n0 = blockIdx.y * 128;
  int kbeg = blockIdx.z * (HID / 2);
  int valid = mt->vend[e] - row0;
  valid = valid > MT ? MT : valid;

  __shared__ __align__(16) ushort_t As[MT * 40];

  int t = threadIdx.x;
  int lane = t & 63, wave = t >> 6;
  int quad = lane >> 4, l16 = lane & 15;

  int sr = t >> 2, sp = t & 3;
  size_t srow = (size_t)(row0 + sr);
  const ushort_t* hr = hbuf + srow * HID + kbeg + sp * 8;
  float smu = muv[srow], srs = rsv[srow];
  const float* gp = lng + (size_t)e * HID + kbeg + sp * 8;
  const float* cp = lnb + (size_t)e * HID + kbeg + sp * 8;

  int ncol = n0 + wave * 32 + l16;
  const ushort_t* bb = W2t + ((size_t)e * DIM + ncol) * HID + kbeg + quad * 8;

  f32x4 acc[4][2];
#pragma unroll
  for (int a = 0; a < 4; a++)
#pragma unroll
    for (int b = 0; b < 2; b++) acc[a][b] = {0.f, 0.f, 0.f, 0.f};

  for (int ks = 0; ks < (HID / 2) / 32; ks++) {
    int kc = ks * 32;
    union { uint4 v; ushort_t u[8]; } hv;
    hv.v = *(const uint4*)(hr + kc);
    float4 g0 = *(const float4*)(gp + kc);
    float4 g1 = *(const float4*)(gp + kc + 4);
    float4 c0 = *(const float4*)(cp + kc);
    float4 c1 = *(const float4*)(cp + kc + 4);
    union { ushort_t u[8]; uint4 v; } pk;
    {
      float gs[8] = {g0.x, g0.y, g0.z, g0.w, g1.x, g1.y, g1.z, g1.w};
      float cs[8] = {c0.x, c0.y, c0.z, c0.w, c1.x, c1.y, c1.z, c1.w};
#pragma unroll
      for (int j = 0; j < 8; j++) {
        float f = (b2f(hv.u[j]) - smu) * srs;
        pk.u[j] = f2b(f * gs[j] + cs[j]);
      }
    }
    __syncthreads();
    *(uint4*)(&As[sr * 40 + sp * 8]) = pk.v;

    bf16x8 bfr[2];
    bfr[0] = *(const bf16x8*)(bb + kc);
    bfr[1] = *(const bf16x8*)(bb + (size_t)16 * HID + kc);
    __syncthreads();
    bf16x8 af[4];
#pragma unroll
    for (int mb = 0; mb < 4; mb++)
      af[mb] = *(const bf16x8*)(&As[(mb * 16 + l16) * 40 + quad * 8]);
#pragma unroll
    for (int mb = 0; mb < 4; mb++)
#pragma unroll
      for (int nb = 0; nb < 2; nb++)
        acc[mb][nb] = __builtin_amdgcn_mfma_f32_16x16x32_bf16(af[mb], bfr[nb], acc[mb][nb], 0, 0, 0);
  }

  bool addb = (blockIdx.z == 0);
#pragma unroll
  for (int mb = 0; mb < 4; mb++) {
#pragma unroll
    for (int i = 0; i < 4; i++) {
      int m = mb * 16 + quad * 4 + i;
      if (m < valid) {
        int tok = ltok[row0 + m];
        float w = lw[row0 + m];
#pragma unroll
        for (int nb = 0; nb < 2; nb++) {
          int n = ncol + nb * 16;
          float v = acc[mb][nb][i] + (addb ? b2[e * DIM + n] : 0.f);
          atomicAdd(out + (size_t)tok * DIM + n, w * v);
        }
      }
    }
  }
}

extern "C" void kernel_launch(void* const* d_in, const int* in_sizes, int n_in,
                              void* d_out, int out_size, void* d_ws, size_t ws_size,
                              hipStream_t stream) {
  const float* x = (const float*)d_in[0];
  const float* Wg = (const float*)d_in[1];
  const float* W1 = (const float*)d_in[2];
  const float* b1 = (const float*)d_in[3];
  const float* lng = (const float*)d_in[4];
  const float* lnb = (const float*)d_in[5];
  const float* W2 = (const float*)d_in[6];
  const float* b2 = (const float*)d_in[7];
  float* out = (float*)d_out;

  char* ws = (char*)d_ws;
  Meta* meta = (Meta*)(ws + OFF_META);
  int* sel = (int*)(ws + OFF_SEL);
  float* wts = (float*)(ws + OFF_WTS);
  int* ltok = (int*)(ws + OFF_LTOK);
  float* lw = (float*)(ws + OFF_LW);
  float* muv = (float*)(ws + OFF_MU);
  float* rsv = (float*)(ws + OFF_RS);
  ushort_t* xbf = (ushort_t*)(ws + OFF_XBF);
  ushort_t* hbuf = (ushort_t*)(ws + OFF_H);
  ushort_t* W1t = (ushort_t*)(ws + OFF_W1T);
  ushort_t* W2t = (ushort_t*)(ws + OFF_W2T);

  hipMemsetAsync(ws, 0, 4096, stream);  // zero Meta (counts)
  hipMemsetAsync(d_out, 0, (size_t)TOKENS * DIM * sizeof(float), stream);

  // weight convert+transpose: W1 [E][512][2048] -> W1t [E][2048][512]
  wconv_k<<<dim3(1024, NEXP), 256, 0, stream>>>(W1, W1t, DIM, HID, HID / 32);
  // W2 [E][2048][512] -> W2t [E][512][2048]
  wconv_k<<<dim3(1024, NEXP), 256, 0, stream>>>(W2, W2t, HID, DIM, DIM / 32);

  router_k<<<TOKENS / 4, 256, 0, stream>>>(x, Wg, xbf, sel, wts, meta);
  build_k<<<1, 256, 0, stream>>>(meta, ltok, lw);
  scatter_k<<<(TOKENS + 255) / 256, 256, 0, stream>>>(meta, sel, wts, ltok, lw);
  ffn1_k<<<dim3(MAX_TILES, HID / 128), 256, 0, stream>>>(W1t, b1, meta, ltok, xbf, hbuf);
  stats_k<<<MAX_ROWS, 256, 0, stream>>>(ltok, hbuf, muv, rsv);
  ffn2_k<<<dim3(MAX_TILES, DIM / 128, 2), 256, 0, stream>>>(W2t, b2, lng, lnb, meta, ltok,
                                                            lw, hbuf, muv, rsv, out);
}

// Round 3
// 278.747 us; speedup vs baseline: 1.2848x; 1.2446x over previous
//
#include <hip/hip_runtime.h>
#include <hip/hip_bf16.h>

#define TOKENS 2048
#define DIM 512
#define NEXP 16
#define HID 2048
#define CAP 320                 /* rows per expert (mean 256, +4 sigma margin) */
#define NTPE (CAP / 64)         /* 5 m-tiles per expert */
#define MTILES (NEXP * NTPE)    /* 80 */
#define NROWS (NEXP * CAP)      /* 5120 */

typedef unsigned short ushort_t;
typedef __attribute__((ext_vector_type(8))) __bf16 bf16x8;
typedef __attribute__((ext_vector_type(4))) float f32x4;

// workspace byte offsets (total 90,260,480 <= known-good 90.3MB)
#define OFF_CNT 0
#define OFF_LTOK 1024
#define OFF_LW 21504
#define OFF_S1 41984
#define OFF_S2 62464
#define OFF_XBF 82944        /* 2048*512*2 = 2,097,152 -> ends 2,180,096 */
#define OFF_H 2180096        /* 5120*2048*2 = 20,971,520 -> ends 23,151,616 */
#define OFF_W1T 23151616     /* 33,554,432 -> ends 56,706,048 */
#define OFF_W2T 56706048     /* 33,554,432 -> ends 90,260,480 */

__device__ __forceinline__ ushort_t f2b(float f) {
  __bf16 b = (__bf16)f;
  return __builtin_bit_cast(unsigned short, b);
}
__device__ __forceinline__ float b2f(ushort_t u) {
  return __builtin_bit_cast(float, (unsigned)u << 16);
}

// ---------- weight convert+transpose (both W1 and W2 in one launch) ---------
// src[E][K][N] f32 -> dst[E][N][K] bf16
__global__ __launch_bounds__(256) void wconv_k(
    const float* __restrict__ W1, const float* __restrict__ W2,
    ushort_t* __restrict__ W1t, ushort_t* __restrict__ W2t,
    int* __restrict__ counts) {
  if (blockIdx.x == 0 && blockIdx.y == 0 && threadIdx.x < NEXP)
    counts[threadIdx.x] = 0;
  int bx = blockIdx.x;
  const float* src;
  ushort_t* dst;
  int K, N, nnt;
  if (bx < 1024) { src = W1; dst = W1t; K = DIM; N = HID; nnt = 64; }
  else { src = W2; dst = W2t; K = HID; N = DIM; nnt = 16; bx -= 1024; }
  int e = blockIdx.y;
  int kt = bx / nnt, ntb = bx % nnt;
  int k0 = kt * 32, n0 = ntb * 32;
  __shared__ ushort_t Ls[32 * 33];
  int t = threadIdx.x;
  int r = t >> 3, c4 = (t & 7) * 4;
  const float* sp = src + ((size_t)e * K + k0 + r) * N + n0 + c4;
  float4 v = *(const float4*)sp;
  Ls[r * 33 + c4 + 0] = f2b(v.x);
  Ls[r * 33 + c4 + 1] = f2b(v.y);
  Ls[r * 33 + c4 + 2] = f2b(v.z);
  Ls[r * 33 + c4 + 3] = f2b(v.w);
  __syncthreads();
  union { ushort_t u[4]; unsigned long long q; } o;
#pragma unroll
  for (int i = 0; i < 4; i++) o.u[i] = Ls[(c4 + i) * 33 + r];
  *(unsigned long long*)(dst + ((size_t)e * N + n0 + r) * K + k0 + c4) = o.q;
}

// ---------------- router: logits, top-2, softmax, slot assignment -----------
// 64 blocks x 256 thr; wave = 1 token at a time (8 tokens/wave).
// Also zeroes d_out and s1/s2.
__global__ __launch_bounds__(256) void router_k(
    const float* __restrict__ x, const float* __restrict__ Wg,
    ushort_t* __restrict__ xbf, int* __restrict__ counts,
    int* __restrict__ ltok, float* __restrict__ lw,
    float* __restrict__ s1, float* __restrict__ s2, float* __restrict__ out) {
  int t = threadIdx.x;
  // zero out (4MB over 64 blocks)
  {
    float4 z = {0.f, 0.f, 0.f, 0.f};
    float4* o4 = (float4*)out + blockIdx.x * 4096 + t;
#pragma unroll
    for (int i = 0; i < 16; i++) o4[i * 256] = z;
  }
  // zero s1/s2
  {
    int idx = blockIdx.x * 256 + t;
    if (idx < NROWS) { s1[idx] = 0.f; s2[idx] = 0.f; }
  }

  __shared__ float xs[4][512];
  __shared__ float lg[4][16];
  __shared__ int lcnt[NEXP];
  __shared__ int ltoks[NEXP][64];
  __shared__ float lws[NEXP][64];
  __shared__ int base_s[NEXP];

  if (t < NEXP) lcnt[t] = 0;
  __syncthreads();

  int lane = t & 63, w = t >> 6;
  int dq = lane >> 2, e4 = lane & 3;
  const float* wgp = Wg + dq * NEXP + e4 * 4;

  for (int it = 0; it < 8; it++) {
    int tok = blockIdx.x * 32 + w * 8 + it;
    const float* xr = x + (size_t)tok * DIM + lane * 8;
    float4 xa = *(const float4*)xr;
    float4 xb = *(const float4*)(xr + 4);
    union { ushort_t u[8]; uint4 v; } pk;
    pk.u[0] = f2b(xa.x); pk.u[1] = f2b(xa.y); pk.u[2] = f2b(xa.z); pk.u[3] = f2b(xa.w);
    pk.u[4] = f2b(xb.x); pk.u[5] = f2b(xb.y); pk.u[6] = f2b(xb.z); pk.u[7] = f2b(xb.w);
    *(uint4*)(xbf + (size_t)tok * DIM + lane * 8) = pk.v;
    *(float4*)&xs[w][lane * 8] = xa;
    *(float4*)&xs[w][lane * 8 + 4] = xb;

    float4 a = {0.f, 0.f, 0.f, 0.f};
#pragma unroll
    for (int kk = 0; kk < 32; kk++) {
      float xv = xs[w][kk * 16 + dq];
      float4 g = *(const float4*)(wgp + kk * 16 * NEXP);
      a.x += xv * g.x; a.y += xv * g.y; a.z += xv * g.z; a.w += xv * g.w;
    }
#pragma unroll
    for (int off = 32; off >= 4; off >>= 1) {
      a.x += __shfl_down(a.x, off);
      a.y += __shfl_down(a.y, off);
      a.z += __shfl_down(a.z, off);
      a.w += __shfl_down(a.w, off);
    }
    if (lane < 4) *(float4*)&lg[w][lane * 4] = a;
    if (lane == 0) {
      int i0 = 0;
      float v0 = lg[w][0];
#pragma unroll
      for (int e = 1; e < NEXP; e++)
        if (lg[w][e] > v0) { v0 = lg[w][e]; i0 = e; }
      int i1 = -1;
      float v1 = -3.4e38f;
#pragma unroll
      for (int e = 0; e < NEXP; e++)
        if (e != i0 && lg[w][e] > v1) { v1 = lg[w][e]; i1 = e; }
      float ex = __expf(v1 - v0);
      float w0 = 1.f / (1.f + ex);
      int p0 = atomicAdd(&lcnt[i0], 1);
      ltoks[i0][p0] = tok;
      lws[i0][p0] = w0;
      int p1 = atomicAdd(&lcnt[i1], 1);
      ltoks[i1][p1] = tok;
      lws[i1][p1] = ex / (1.f + ex);
    }
  }
  __syncthreads();
  if (t < NEXP) base_s[t] = atomicAdd(&counts[t], lcnt[t]);
  __syncthreads();
  int e = t >> 4, i0 = t & 15;
  int n = lcnt[e], b = base_s[e];
  for (int i = i0; i < n; i += 16) {
    int slot = b + i;
    if (slot < CAP) {
      ltok[e * CAP + slot] = ltoks[e][i];
      lw[e * CAP + slot] = lws[e][i];
    }
  }
}

// ---------------- GEMM1: h = silu(x @ W1 + b1), store bf16 + row stats ------
// W1t: [E][H][D] bf16 (k=D contiguous)
__global__ __launch_bounds__(256) void ffn1_k(
    const ushort_t* __restrict__ W1t, const float* __restrict__ b1,
    const int* __restrict__ counts, const int* __restrict__ ltok,
    const ushort_t* __restrict__ xbf, ushort_t* __restrict__ hbuf,
    float* __restrict__ s1, float* __restrict__ s2) {
  int e = blockIdx.x / NTPE, mt = blockIdx.x % NTPE;
  int cnt = counts[e];
  if (cnt - mt * 64 <= 0) return;
  int row0 = e * CAP + mt * 64;
  int h0 = blockIdx.y * 128;

  __shared__ __align__(16) ushort_t As[64 * 40];

  int t = threadIdx.x;
  int lane = t & 63, wave = t >> 6;
  int quad = lane >> 4, l16 = lane & 15;

  int sr = t >> 2, sp = t & 3;
  int stok = ltok[row0 + sr];
  const ushort_t* sx = xbf + (size_t)(stok < 0 ? 0 : stok) * DIM + sp * 8;
  bool sok = stok >= 0;

  int ncol = h0 + wave * 32 + l16;
  const ushort_t* bb = W1t + ((size_t)e * HID + ncol) * DIM + quad * 8;

  f32x4 acc[4][2];
#pragma unroll
  for (int a = 0; a < 4; a++)
#pragma unroll
    for (int b = 0; b < 2; b++) acc[a][b] = {0.f, 0.f, 0.f, 0.f};

  for (int ks = 0; ks < DIM / 32; ks++) {
    int kc = ks * 32;
    uint4 av = {0u, 0u, 0u, 0u};
    if (sok) av = *(const uint4*)(sx + kc);
    __syncthreads();
    *(uint4*)(&As[sr * 40 + sp * 8]) = av;

    bf16x8 bfr[2];
    bfr[0] = *(const bf16x8*)(bb + kc);
    bfr[1] = *(const bf16x8*)(bb + (size_t)16 * DIM + kc);
    __syncthreads();
    bf16x8 af[4];
#pragma unroll
    for (int mb = 0; mb < 4; mb++)
      af[mb] = *(const bf16x8*)(&As[(mb * 16 + l16) * 40 + quad * 8]);
#pragma unroll
    for (int mb = 0; mb < 4; mb++)
#pragma unroll
      for (int nb = 0; nb < 2; nb++)
        acc[mb][nb] = __builtin_amdgcn_mfma_f32_16x16x32_bf16(af[mb], bfr[nb], acc[mb][nb], 0, 0, 0);
  }

  float bia0 = b1[e * HID + ncol];
  float bia1 = b1[e * HID + ncol + 16];
#pragma unroll
  for (int mb = 0; mb < 4; mb++) {
#pragma unroll
    for (int i = 0; i < 4; i++) {
      int m = mb * 16 + quad * 4 + i;
      size_t rowg = (size_t)(row0 + m);
      float v0 = acc[mb][0][i] + bia0;
      v0 = v0 / (1.f + __expf(-v0));
      float v1 = acc[mb][1][i] + bia1;
      v1 = v1 / (1.f + __expf(-v1));
      hbuf[rowg * HID + ncol] = f2b(v0);
      hbuf[rowg * HID + ncol + 16] = f2b(v1);
      float ps = v0 + v1, qs = v0 * v0 + v1 * v1;
      ps += __shfl_down(ps, 8); qs += __shfl_down(qs, 8);
      ps += __shfl_down(ps, 4); qs += __shfl_down(qs, 4);
      ps += __shfl_down(ps, 2); qs += __shfl_down(qs, 2);
      ps += __shfl_down(ps, 1); qs += __shfl_down(qs, 1);
      if (l16 == 0) {
        atomicAdd(&s1[rowg], ps);
        atomicAdd(&s2[rowg], qs);
      }
    }
  }
}

// ---------------- GEMM2: out[t] += w * (LN(h) @ W2 + b2) --------------------
// W2t: [E][D][H] bf16 (k=H contiguous). K split in 2 via blockIdx.z.
__global__ __launch_bounds__(256) void ffn2_k(
    const ushort_t* __restrict__ W2t, const float* __restrict__ b2,
    const float* __restrict__ lng, const float* __restrict__ lnb,
    const int* __restrict__ counts, const int* __restrict__ ltok,
    const float* __restrict__ lw, const ushort_t* __restrict__ hbuf,
    const float* __restrict__ s1, const float* __restrict__ s2,
    float* __restrict__ out) {
  int e = blockIdx.x / NTPE, mt = blockIdx.x % NTPE;
  int cnt = counts[e];
  int valid = cnt - mt * 64;
  if (valid <= 0) return;
  valid = valid > 64 ? 64 : valid;
  int row0 = e * CAP + mt * 64;
  int n0 = blockIdx.y * 128;
  int kbeg = blockIdx.z * (HID / 2);

  __shared__ __align__(16) ushort_t As[64 * 40];

  int t = threadIdx.x;
  int lane = t & 63, wave = t >> 6;
  int quad = lane >> 4, l16 = lane & 15;

  int sr = t >> 2, sp = t & 3;
  size_t srow = (size_t)(row0 + sr);
  const ushort_t* hr = hbuf + srow * HID + kbeg + sp * 8;
  float smu = s1[srow] * (1.f / HID);
  float var = s2[srow] * (1.f / HID) - smu * smu;
  float srs = rsqrtf(var + 1e-5f);
  const float* gp = lng + (size_t)e * HID + kbeg + sp * 8;
  const float* cp = lnb + (size_t)e * HID + kbeg + sp * 8;

  int ncol = n0 + wave * 32 + l16;
  const ushort_t* bb = W2t + ((size_t)e * DIM + ncol) * HID + kbeg + quad * 8;

  f32x4 acc[4][2];
#pragma unroll
  for (int a = 0; a < 4; a++)
#pragma unroll
    for (int b = 0; b < 2; b++) acc[a][b] = {0.f, 0.f, 0.f, 0.f};

  for (int ks = 0; ks < (HID / 2) / 32; ks++) {
    int kc = ks * 32;
    union { uint4 v; ushort_t u[8]; } hv;
    hv.v = *(const uint4*)(hr + kc);
    float4 g0 = *(const float4*)(gp + kc);
    float4 g1 = *(const float4*)(gp + kc + 4);
    float4 c0 = *(const float4*)(cp + kc);
    float4 c1 = *(const float4*)(cp + kc + 4);
    union { ushort_t u[8]; uint4 v; } pk;
    {
      float gs[8] = {g0.x, g0.y, g0.z, g0.w, g1.x, g1.y, g1.z, g1.w};
      float cs[8] = {c0.x, c0.y, c0.z, c0.w, c1.x, c1.y, c1.z, c1.w};
#pragma unroll
      for (int j = 0; j < 8; j++) {
        float f = (b2f(hv.u[j]) - smu) * srs;
        pk.u[j] = f2b(f * gs[j] + cs[j]);
      }
    }
    __syncthreads();
    *(uint4*)(&As[sr * 40 + sp * 8]) = pk.v;

    bf16x8 bfr[2];
    bfr[0] = *(const bf16x8*)(bb + kc);
    bfr[1] = *(const bf16x8*)(bb + (size_t)16 * HID + kc);
    __syncthreads();
    bf16x8 af[4];
#pragma unroll
    for (int mb = 0; mb < 4; mb++)
      af[mb] = *(const bf16x8*)(&As[(mb * 16 + l16) * 40 + quad * 8]);
#pragma unroll
    for (int mb = 0; mb < 4; mb++)
#pragma unroll
      for (int nb = 0; nb < 2; nb++)
        acc[mb][nb] = __builtin_amdgcn_mfma_f32_16x16x32_bf16(af[mb], bfr[nb], acc[mb][nb], 0, 0, 0);
  }

  bool addb = (blockIdx.z == 0);
#pragma unroll
  for (int mb = 0; mb < 4; mb++) {
#pragma unroll
    for (int i = 0; i < 4; i++) {
      int m = mb * 16 + quad * 4 + i;
      if (m < valid) {
        int tok = ltok[row0 + m];
        float w = lw[row0 + m];
#pragma unroll
        for (int nb = 0; nb < 2; nb++) {
          int n = ncol + nb * 16;
          float v = acc[mb][nb][i] + (addb ? b2[e * DIM + n] : 0.f);
          atomicAdd(out + (size_t)tok * DIM + n, w * v);
        }
      }
    }
  }
}

extern "C" void kernel_launch(void* const* d_in, const int* in_sizes, int n_in,
                              void* d_out, int out_size, void* d_ws, size_t ws_size,
                              hipStream_t stream) {
  const float* x = (const float*)d_in[0];
  const float* Wg = (const float*)d_in[1];
  const float* W1 = (const float*)d_in[2];
  const float* b1 = (const float*)d_in[3];
  const float* lng = (const float*)d_in[4];
  const float* lnb = (const float*)d_in[5];
  const float* W2 = (const float*)d_in[6];
  const float* b2 = (const float*)d_in[7];
  float* out = (float*)d_out;

  char* ws = (char*)d_ws;
  int* counts = (int*)(ws + OFF_CNT);
  int* ltok = (int*)(ws + OFF_LTOK);
  float* lw = (float*)(ws + OFF_LW);
  float* s1 = (float*)(ws + OFF_S1);
  float* s2 = (float*)(ws + OFF_S2);
  ushort_t* xbf = (ushort_t*)(ws + OFF_XBF);
  ushort_t* hbuf = (ushort_t*)(ws + OFF_H);
  ushort_t* W1t = (ushort_t*)(ws + OFF_W1T);
  ushort_t* W2t = (ushort_t*)(ws + OFF_W2T);

  wconv_k<<<dim3(2048, NEXP), 256, 0, stream>>>(W1, W2, W1t, W2t, counts);
  router_k<<<64, 256, 0, stream>>>(x, Wg, xbf, counts, ltok, lw, s1, s2, out);
  ffn1_k<<<dim3(MTILES, HID / 128), 256, 0, stream>>>(W1t, b1, counts, ltok, xbf, hbuf, s1, s2);
  ffn2_k<<<dim3(MTILES, DIM / 128, 2), 256, 0, stream>>>(W2t, b2, lng, lnb, counts, ltok,
                                                         lw, hbuf, s1, s2, out);
}